// Round 4
// baseline (169.601 us; speedup 1.0000x reference)
//
#include <hip/hip_runtime.h>

#define N_NODES 4096
#define F_IN    512
#define NH1     8
#define F1      64   // NH1*ND1
#define C2      16
#define MAXDEG  128  // Binomial(4095,0.005): mean 20.5, max ~50; 128 unreachable

#define GEMM_BLKS 256    // 16 rows each -> 4096 rows
#define SCAN_BLKS 1024   // 4 rows each (1 row/wave)

__device__ __forceinline__ float wave_sum(float v) {
    for (int o = 32; o >= 1; o >>= 1) v += __shfl_xor(v, o, 64);
    return v;
}

// async global->LDS, 16B per lane; dest = wave-uniform base + lane*16
typedef __attribute__((address_space(3))) unsigned char lds_uchar;
typedef __attribute__((address_space(1))) const unsigned char g_uchar;
__device__ __forceinline__ void gload_lds16(const void* g, void* lds) {
    __builtin_amdgcn_global_load_lds((g_uchar*)g, (lds_uchar*)lds, 16, 0, 0);
}

// ---------------------------------------------------------------------------
// Per-wave adjacency element-width detection from the first 4 KB of adj.
// Same byte-position classification rules as the validated one-block kernel,
// reduced with wave ballots. Self-loop at adj[0][0] guarantees >=1 nonzero
// for every width. Wave-uniform result.
// ---------------------------------------------------------------------------
__device__ __forceinline__ int detect_width_wave(const unsigned char* __restrict__ adj,
                                                 int l) {
    bool nz0 = false, nz1 = false, nz2 = false, nz3 = false;
    unsigned int mx = 0u;
    const uint4* p = (const uint4*)adj;
    #pragma unroll
    for (int i = 0; i < 4; ++i) {          // 64 lanes * 4 * 16B = 4 KB
        uint4 q = p[l + 64 * i];
        unsigned int wd[4] = {q.x, q.y, q.z, q.w};
        #pragma unroll
        for (int k = 0; k < 4; ++k) {
            unsigned int v = wd[k];
            unsigned int b0 = v & 0xffu, b1 = (v >> 8) & 0xffu;
            unsigned int b2 = (v >> 16) & 0xffu, b3 = (v >> 24) & 0xffu;
            if (b0) { nz0 = true; mx = mx > b0 ? mx : b0; }
            if (b1) { nz1 = true; mx = mx > b1 ? mx : b1; }
            if (b2) { nz2 = true; mx = mx > b2 ? mx : b2; }
            if (b3) { nz3 = true; mx = mx > b3 ? mx : b3; }
        }
    }
    const bool a0 = __any(nz0), a1 = __any(nz1), a2 = __any(nz2), a3 = __any(nz3);
    const bool big = __any(mx > 1u);
    if (!a1 && !a2 && !a3) return 4;   // int32 {0,1}: only byte 0 of each dword
    if (!a0 && !a1)        return 4;   // fp32 1.0f: bytes 2,3
    if (!a0 && !a2)        return 2;   // f16 1.0: odd bytes only
    if (!big)              return 1;   // bool/uint8 {0,1}
    return 2;                          // bf16 1.0
}

// ---------------------------------------------------------------------------
// Fused front-end, occupancy-first redesign:
//   blocks [0, GEMM_BLKS):   GEMM1 (+fused es/ed). 16 rows/block, 4 out/lane.
//                            LDS = W-tile ONLY (16 KB), staged via
//                            global_load_lds (no VGPR prefetch). x-row values
//                            are wave-uniform -> scalar (SMEM) loads via a
//                            readfirstlane-hoisted pointer; zero LDS for x.
//   blocks [GEMM_BLKS, ...): CSR row scan, 1 row/wave, per-wave width detect.
// LDS 16.5 KB, low VGPR => up to 8 blocks/CU (was 3 at 49.7 KB / 136 VGPR).
// ---------------------------------------------------------------------------
__global__ __launch_bounds__(256) void frontend_kernel(
        const unsigned char* __restrict__ adj,
        unsigned short* __restrict__ neigh, int* __restrict__ deg,
        const float* __restrict__ x, const float* __restrict__ W1,
        const float* __restrict__ asrc, const float* __restrict__ adst,
        float* __restrict__ h1, float* __restrict__ es, float* __restrict__ ed) {
    __shared__ __align__(16) float wt[4096];   // 64x64 W-tile, 16 KB
    __shared__ int scnt[4];
    const int t = threadIdx.x;
    const int wv = t >> 6;
    const int l = t & 63;

    if (blockIdx.x < GEMM_BLKS) {
        // ---- GEMM1: rows row0..row0+15, cols 0..63 ----
        const int row0 = blockIdx.x * 16;
        const int c = l;
        const int wvu = __builtin_amdgcn_readfirstlane(wv);  // SGPR wave id

        // stage W tile 0 (16 KB, 4 x 1KB segments per wave)
        {
            const char* src = (const char*)W1;
            #pragma unroll
            for (int i2 = 0; i2 < 4; ++i2) {
                const int seg = wvu * 4 + i2;
                gload_lds16(src + seg * 1024 + l * 16, (char*)wt + seg * 1024);
            }
        }

        float a0 = 0.f, a1 = 0.f, a2 = 0.f, a3 = 0.f;
        const float* xb = x + (size_t)row0 * F_IN;   // uniform base
        #pragma unroll 1
        for (int tile = 0; tile < 8; ++tile) {
            __syncthreads();   // drains global_load_lds (vmcnt) + publishes wt
            // x rows for this wave (wave-uniform addresses -> scalar loads)
            const float* xr0 = xb + (size_t)(wvu     ) * F_IN + tile * 64;
            const float* xr1 = xb + (size_t)(wvu +  4) * F_IN + tile * 64;
            const float* xr2 = xb + (size_t)(wvu +  8) * F_IN + tile * 64;
            const float* xr3 = xb + (size_t)(wvu + 12) * F_IN + tile * 64;
            #pragma unroll
            for (int kk = 0; kk < 64; kk += 2) {
                const float w0 = wt[(kk + 0) * 64 + c];
                const float w1 = wt[(kk + 1) * 64 + c];
                a0 += xr0[kk] * w0 + xr0[kk + 1] * w1;
                a1 += xr1[kk] * w0 + xr1[kk + 1] * w1;
                a2 += xr2[kk] * w0 + xr2[kk + 1] * w1;
                a3 += xr3[kk] * w0 + xr3[kk + 1] * w1;
            }
            __syncthreads();   // all reads of wt done
            if (tile < 7) {    // issue next tile's async loads
                const char* src = (const char*)W1 + (size_t)(tile + 1) * 16384;
                #pragma unroll
                for (int i2 = 0; i2 < 4; ++i2) {
                    const int seg = wvu * 4 + i2;
                    gload_lds16(src + seg * 1024 + l * 16, (char*)wt + seg * 1024);
                }
            }
        }

        // epilogue: h1 + fused es/ed for the 4 rows
        float acc[4] = {a0, a1, a2, a3};
        #pragma unroll
        for (int r = 0; r < 4; ++r) {
            const int n = row0 + wvu + 4 * r;
            h1[(size_t)n * F1 + c] = acc[r];
            float s = acc[r] * asrc[c];
            float d = acc[r] * adst[c];
            s += __shfl_xor(s, 1); s += __shfl_xor(s, 2); s += __shfl_xor(s, 4);
            d += __shfl_xor(d, 1); d += __shfl_xor(d, 2); d += __shfl_xor(d, 4);
            if ((c & 7) == 0) {
                es[n * NH1 + (c >> 3)] = s;
                ed[n * NH1 + (c >> 3)] = d;
            }
        }
    } else {
        // ---- CSR scan: one wave per row; width derived per-wave ----
        const int w = detect_width_wave(adj, l);
        const int row = (blockIdx.x - GEMM_BLKS) * 4 + wv;
        int* cnt = scnt + wv;
        if (l == 0) *cnt = 0;              // same-wave DS ops are in-order
        unsigned short* outp = neigh + (size_t)row * MAXDEG;
        if (w == 1) {
            const uint4* p = (const uint4*)(adj + (size_t)row * N_NODES);
            uint4 v[4];
            #pragma unroll
            for (int i = 0; i < 4; ++i) v[i] = p[l + 64 * i];   // 4 loads in flight
            #pragma unroll
            for (int i = 0; i < 4; ++i) {
                if ((v[i].x | v[i].y | v[i].z | v[i].w) == 0u) continue;
                unsigned int wd[4] = {v[i].x, v[i].y, v[i].z, v[i].w};
                int base = (l + 64 * i) * 16;
                for (int q = 0; q < 4; ++q) {
                    unsigned int word = wd[q];
                    for (int bb = 0; bb < 4; ++bb) {
                        if ((word >> (8 * bb)) & 0xffu) {
                            int pos = atomicAdd(cnt, 1);
                            if (pos < MAXDEG) outp[pos] = (unsigned short)(base + q * 4 + bb);
                        }
                    }
                }
            }
        } else if (w == 2) {
            const uint4* p = (const uint4*)(adj + (size_t)row * N_NODES * 2);
            uint4 v[8];
            #pragma unroll
            for (int i = 0; i < 8; ++i) v[i] = p[l + 64 * i];
            #pragma unroll
            for (int i = 0; i < 8; ++i) {
                if ((v[i].x | v[i].y | v[i].z | v[i].w) == 0u) continue;
                unsigned int wd[4] = {v[i].x, v[i].y, v[i].z, v[i].w};
                int base = (l + 64 * i) * 8;
                for (int q = 0; q < 4; ++q) {
                    unsigned int word = wd[q];
                    if (word & 0xffffu) {
                        int pos = atomicAdd(cnt, 1);
                        if (pos < MAXDEG) outp[pos] = (unsigned short)(base + q * 2);
                    }
                    if (word >> 16) {
                        int pos = atomicAdd(cnt, 1);
                        if (pos < MAXDEG) outp[pos] = (unsigned short)(base + q * 2 + 1);
                    }
                }
            }
        } else {
            const uint4* p = (const uint4*)(adj + (size_t)row * N_NODES * 4);
            #pragma unroll
            for (int b = 0; b < 2; ++b) {
                uint4 v[8];
                #pragma unroll
                for (int i = 0; i < 8; ++i) v[i] = p[l + 64 * (b * 8 + i)];
                #pragma unroll
                for (int i = 0; i < 8; ++i) {
                    if ((v[i].x | v[i].y | v[i].z | v[i].w) == 0u) continue;
                    unsigned int wd[4] = {v[i].x, v[i].y, v[i].z, v[i].w};
                    int base = (l + 64 * (b * 8 + i)) * 4;
                    for (int q = 0; q < 4; ++q) {
                        if (wd[q]) {
                            int pos = atomicAdd(cnt, 1);
                            if (pos < MAXDEG) outp[pos] = (unsigned short)(base + q);
                        }
                    }
                }
            }
        }
        if (l == 0) deg[row] = min(*cnt, MAXDEG);   // same-wave read-after-atomic
    }
}

// ---------------------------------------------------------------------------
// Attention layer 1 + ELU + fused gemm2/scores2 (R3-validated, verbatim).
// ---------------------------------------------------------------------------
__global__ __launch_bounds__(256) void attn1_kernel(
        const unsigned short* __restrict__ neigh, const int* __restrict__ deg,
        const float* __restrict__ h1, const float* __restrict__ es,
        const float* __restrict__ ed, const float* __restrict__ W2,
        const float* __restrict__ a2s, const float* __restrict__ a2d,
        float* __restrict__ h2, float* __restrict__ es2, float* __restrict__ ed2) {
    __shared__ float pbufA[4 * 576];
    __shared__ float arowA[4 * 64];
    const int t = threadIdx.x;
    const int wv = t >> 6;
    const int l = t & 63;
    const int i = blockIdx.x * 4 + wv;
    float* pw   = pbufA + wv * 576;
    float* arow = arowA + wv * 64;
    const int hq = l >> 3;

    const int K = deg[i];
    const unsigned short* lst = neigh + (size_t)i * MAXDEG;

    float plsum[NH1];
    #pragma unroll
    for (int h = 0; h < NH1; ++h) plsum[h] = 0.f;
    const float4 e0 = *(const float4*)(es + (size_t)i * NH1);
    const float4 e1 = *(const float4*)(es + (size_t)i * NH1 + 4);
    const float esi[NH1] = {e0.x, e0.y, e0.z, e0.w, e1.x, e1.y, e1.z, e1.w};
    float acc = 0.f;

    for (int t0 = 0; t0 < K; t0 += 64) {
        const int tc = min(64, K - t0);
        const bool valid = l < tc;
        const int j = valid ? (int)lst[t0 + l] : 0;
        const float4 d0v = *(const float4*)(ed + (size_t)j * NH1);
        const float4 d1v = *(const float4*)(ed + (size_t)j * NH1 + 4);
        const float edv[NH1] = {d0v.x, d0v.y, d0v.z, d0v.w,
                                d1v.x, d1v.y, d1v.z, d1v.w};
        #pragma unroll
        for (int h = 0; h < NH1; ++h) {
            float v = esi[h] + edv[h];
            v = (v >= 0.f) ? v : 0.2f * v;      // LeakyReLU(0.2)
            float p = valid ? __expf(v) : 0.f;  // no max-shift: |v|<~4
            plsum[h] += p;
            pw[l * 9 + h] = p;
        }
        __builtin_amdgcn_wave_barrier();
        const int tcPad = (tc + 7) & ~7;
        for (int u = 0; u < tcPad; u += 8) {
            #pragma unroll
            for (int vv = 0; vv < 8; ++vv) {
                const int slot = u + vv;
                const int jn = __shfl(j, slot);     // broadcast neighbor id
                acc += pw[slot * 9 + hq] * h1[(size_t)jn * F1 + l];
            }
        }
        __builtin_amdgcn_wave_barrier();
    }
    float lsum[NH1];
    #pragma unroll
    for (int h = 0; h < NH1; ++h) lsum[h] = wave_sum(plsum[h]);
    float o = acc / lsum[hq];
    float a1v = (o > 0.f) ? o : (__expf(o) - 1.f);  // ELU

    // fused gemm2 + scores2 (row-local, per-wave)
    arow[l] = a1v;
    __builtin_amdgcn_wave_barrier();
    const int cc = l & 15;
    const int kg = l >> 4;
    float hacc = 0.f;
    #pragma unroll
    for (int k = 0; k < 16; ++k)
        hacc += arow[kg * 16 + k] * W2[(kg * 16 + k) * C2 + cc];
    hacc += __shfl_xor(hacc, 16);
    hacc += __shfl_xor(hacc, 32);
    if (l < C2) h2[(size_t)i * C2 + l] = hacc;
    float s2 = hacc * a2s[cc];
    float d2 = hacc * a2d[cc];
    s2 += __shfl_xor(s2, 1); s2 += __shfl_xor(s2, 2);
    s2 += __shfl_xor(s2, 4); s2 += __shfl_xor(s2, 8);
    d2 += __shfl_xor(d2, 1); d2 += __shfl_xor(d2, 2);
    d2 += __shfl_xor(d2, 4); d2 += __shfl_xor(d2, 8);
    if (l == 0) { es2[i] = s2; ed2[i] = d2; }
}

// ---------------------------------------------------------------------------
// Attention layer 2 — LDS-free (R3-validated, verbatim).
// ---------------------------------------------------------------------------
__global__ __launch_bounds__(256) void attn2_kernel(
        const unsigned short* __restrict__ neigh, const int* __restrict__ deg,
        const float* __restrict__ h2, const float* __restrict__ es2,
        const float* __restrict__ ed2, float* __restrict__ out) {
    const int t = threadIdx.x;
    const int wv = t >> 6;
    const int l = t & 63;
    const int i = blockIdx.x * 4 + wv;
    const int c = l & 15;
    const int g = l >> 4;

    const int K = deg[i];
    const unsigned short* lst = neigh + (size_t)i * MAXDEG;

    float plsum = 0.f, acc = 0.f;
    const float esi = es2[i];
    for (int t0 = 0; t0 < K; t0 += 64) {
        const int tc = min(64, K - t0);
        const bool valid = l < tc;
        const int j = valid ? (int)lst[t0 + l] : 0;
        float v = esi + ed2[j];
        v = (v >= 0.f) ? v : 0.2f * v;
        float p = valid ? __expf(v) : 0.f;   // no max-shift
        plsum += p;
        const int tcPad = (tc + 3) & ~3;
        for (int u = g; u < tcPad; u += 4) {
            const int jn = __shfl(j, u);     // per-group broadcast
            const float pv = __shfl(p, u);
            acc += pv * h2[(size_t)jn * C2 + c];
        }
    }
    float lsum = wave_sum(plsum);    // wave-uniform
    acc += __shfl_xor(acc, 16);
    acc += __shfl_xor(acc, 32);
    if (l < C2) out[(size_t)i * C2 + l] = acc / lsum;
}

extern "C" void kernel_launch(void* const* d_in, const int* in_sizes, int n_in,
                              void* d_out, int out_size, void* d_ws, size_t ws_size,
                              hipStream_t stream) {
    const float* x           = (const float*)d_in[0];
    const unsigned char* adj = (const unsigned char*)d_in[1];
    const float* W1          = (const float*)d_in[2];
    const float* a1src       = (const float*)d_in[3];
    const float* a1dst       = (const float*)d_in[4];
    const float* W2          = (const float*)d_in[5];
    const float* a2src       = (const float*)d_in[6];
    const float* a2dst       = (const float*)d_in[7];
    float* out = (float*)d_out;

    // workspace layout (~2.6 MB), all offsets 256B-aligned
    char* ws = (char*)d_ws;
    size_t off = 0;
    off += 256;                                       // (reserved)
    unsigned short* neigh = (unsigned short*)(ws + off);
    off += (size_t)N_NODES * MAXDEG * 2;              // 1 MB
    int* deg = (int*)(ws + off);                      off += (size_t)N_NODES * 4;
    float* h1 = (float*)(ws + off);                   off += (size_t)N_NODES * F1 * 4;
    float* es1 = (float*)(ws + off);                  off += (size_t)N_NODES * NH1 * 4;
    float* ed1 = (float*)(ws + off);                  off += (size_t)N_NODES * NH1 * 4;
    float* h2 = (float*)(ws + off);                   off += (size_t)N_NODES * C2 * 4;
    float* es2 = (float*)(ws + off);                  off += (size_t)N_NODES * 4;
    float* ed2 = (float*)(ws + off);                  off += (size_t)N_NODES * 4;

    hipLaunchKernelGGL(frontend_kernel, dim3(GEMM_BLKS + SCAN_BLKS), dim3(256), 0, stream,
                       adj, neigh, deg, x, W1, a1src, a1dst, h1, es1, ed1);
    hipLaunchKernelGGL(attn1_kernel, dim3(N_NODES / 4), dim3(256), 0, stream,
                       neigh, deg, h1, es1, ed1, W2, a2src, a2dst, h2, es2, ed2);
    hipLaunchKernelGGL(attn2_kernel, dim3(N_NODES / 4), dim3(256), 0, stream,
                       neigh, deg, h2, es2, ed2, out);
}

// Round 5
// 138.019 us; speedup vs baseline: 1.2288x; 1.2288x over previous
//
#include <hip/hip_runtime.h>

#define N_NODES 4096
#define F_IN    512
#define NH1     8
#define F1      64   // NH1*ND1
#define C2      16
#define MAXDEG  128  // Binomial(4095,0.005): mean 20.5, max ~50; 128 unreachable

#define GEMM_BLKS 512    // 8 rows each -> 4096 rows
#define SCAN_BLKS 1024   // 4 rows each (1 row/wave)

__device__ __forceinline__ float wave_sum(float v) {
    for (int o = 32; o >= 1; o >>= 1) v += __shfl_xor(v, o, 64);
    return v;
}

// ---------------------------------------------------------------------------
// Per-wave adjacency element-width detection from the first 4 KB of adj.
// Validated classification rules; wave-ballot reduction; wave-uniform result.
// ---------------------------------------------------------------------------
__device__ __forceinline__ int detect_width_wave(const unsigned char* __restrict__ adj,
                                                 int l) {
    bool nz0 = false, nz1 = false, nz2 = false, nz3 = false;
    unsigned int mx = 0u;
    const uint4* p = (const uint4*)adj;
    #pragma unroll
    for (int i = 0; i < 4; ++i) {          // 64 lanes * 4 * 16B = 4 KB
        uint4 q = p[l + 64 * i];
        unsigned int wd[4] = {q.x, q.y, q.z, q.w};
        #pragma unroll
        for (int k = 0; k < 4; ++k) {
            unsigned int v = wd[k];
            unsigned int b0 = v & 0xffu, b1 = (v >> 8) & 0xffu;
            unsigned int b2 = (v >> 16) & 0xffu, b3 = (v >> 24) & 0xffu;
            if (b0) { nz0 = true; mx = mx > b0 ? mx : b0; }
            if (b1) { nz1 = true; mx = mx > b1 ? mx : b1; }
            if (b2) { nz2 = true; mx = mx > b2 ? mx : b2; }
            if (b3) { nz3 = true; mx = mx > b3 ? mx : b3; }
        }
    }
    const bool a0 = __any(nz0), a1 = __any(nz1), a2 = __any(nz2), a3 = __any(nz3);
    const bool big = __any(mx > 1u);
    if (!a1 && !a2 && !a3) return 4;   // int32 {0,1}: only byte 0 of each dword
    if (!a0 && !a1)        return 4;   // fp32 1.0f: bytes 2,3
    if (!a0 && !a2)        return 2;   // f16 1.0: odd bytes only
    if (!big)              return 1;   // bool/uint8 {0,1}
    return 2;                          // bf16 1.0
}

// ---------------------------------------------------------------------------
// CSR scan, standalone (ablation + rewrite): 1 row/wave, ZERO atomics.
// Each lane builds a 64-bit nonzero mask over its coalesced 16B chunks,
// then a 6-step shfl_up exclusive prefix places its entries. Neighbor-list
// order is arbitrary (softmax is order-invariant; prior versions used
// atomic completion order).
// ---------------------------------------------------------------------------
__global__ __launch_bounds__(256) void scan_kernel(
        const unsigned char* __restrict__ adj,
        unsigned short* __restrict__ neigh, int* __restrict__ deg) {
    const int t = threadIdx.x;
    const int wv = t >> 6;
    const int l = t & 63;
    const int w = detect_width_wave(adj, l);
    const int row = blockIdx.x * 4 + wv;
    unsigned short* outp = neigh + (size_t)row * MAXDEG;

    unsigned long long mask = 0ull;
    int eshift;
    if (w == 1) {
        eshift = 4;                                  // 16 elements / 16B chunk
        const uint4* p = (const uint4*)(adj + (size_t)row * N_NODES);
        uint4 v[4];
        #pragma unroll
        for (int i = 0; i < 4; ++i) v[i] = p[l + 64 * i];   // 4 loads in flight
        #pragma unroll
        for (int i = 0; i < 4; ++i) {
            unsigned int wd[4] = {v[i].x, v[i].y, v[i].z, v[i].w};
            #pragma unroll
            for (int q = 0; q < 4; ++q) {
                unsigned int x = wd[q];
                // 0x80 in each nonzero byte
                unsigned int tt = (x | ((x & 0x7f7f7f7fu) + 0x7f7f7f7fu)) & 0x80808080u;
                // gather the 4 flag bits into a nibble (no cross-term pollution)
                unsigned int nib = ((tt >> 7) * 0x01020408u) >> 24;
                mask |= (unsigned long long)nib << (16 * i + 4 * q);
            }
        }
    } else if (w == 2) {
        eshift = 3;                                  // 8 elements / 16B chunk
        const uint4* p = (const uint4*)(adj + (size_t)row * N_NODES * 2);
        uint4 v[8];
        #pragma unroll
        for (int i = 0; i < 8; ++i) v[i] = p[l + 64 * i];
        #pragma unroll
        for (int i = 0; i < 8; ++i) {
            unsigned int wd[4] = {v[i].x, v[i].y, v[i].z, v[i].w};
            #pragma unroll
            for (int q = 0; q < 4; ++q) {
                unsigned int x = wd[q];
                unsigned int b = ((x & 0xffffu) ? 1u : 0u) | ((x >> 16) ? 2u : 0u);
                mask |= (unsigned long long)b << (8 * i + 2 * q);
            }
        }
    } else {
        eshift = 2;                                  // 4 elements / 16B chunk
        const uint4* p = (const uint4*)(adj + (size_t)row * N_NODES * 4);
        #pragma unroll
        for (int b2 = 0; b2 < 2; ++b2) {
            uint4 v[8];
            #pragma unroll
            for (int i = 0; i < 8; ++i) v[i] = p[l + 64 * (b2 * 8 + i)];
            #pragma unroll
            for (int i = 0; i < 8; ++i) {
                unsigned int wd[4] = {v[i].x, v[i].y, v[i].z, v[i].w};
                #pragma unroll
                for (int q = 0; q < 4; ++q)
                    if (wd[q]) mask |= 1ull << (4 * (b2 * 8 + i) + q);
            }
        }
    }

    // wave-wide compaction
    const int cnt = __popcll(mask);
    int pfx = cnt;
    #pragma unroll
    for (int o = 1; o < 64; o <<= 1) {
        int up = __shfl_up(pfx, o, 64);
        if (l >= o) pfx += up;
    }
    int base = pfx - cnt;                 // exclusive prefix
    unsigned long long m = mask;
    while (m) {
        const int b = __builtin_ctzll(m);
        m &= m - 1;
        // element index: chunk (b>>eshift) at stride 64 chunks, lane-local offset
        const int e = ((b >> eshift) << (eshift + 6)) + (l << eshift)
                    + (b & ((1 << eshift) - 1));
        if (base < MAXDEG) outp[base] = (unsigned short)e;
        ++base;
    }
    if (l == 63) deg[row] = min(pfx, MAXDEG);
}

// ---------------------------------------------------------------------------
// GEMM1 + fused es/ed, standalone — R1-validated body verbatim (8 rows/block,
// 2 out/lane, xs+wt in LDS, register-prefetch double buffer; one barrier per
// K-tile). No SMEM/DS mixing on the critical path.
// ---------------------------------------------------------------------------
__global__ __launch_bounds__(256) void gemm_kernel(
        const float* __restrict__ x, const float* __restrict__ W1,
        const float* __restrict__ asrc, const float* __restrict__ adst,
        float* __restrict__ h1, float* __restrict__ es, float* __restrict__ ed) {
    __shared__ __align__(16) float smem[4096 + 2 * 4096];  // xs + wt dbuf, 48 KB
    const int t = threadIdx.x;

    float* xs  = smem;          // 8 x 512 floats = 16 KB
    float* wt0 = smem + 4096;   // 64 x 64 tile, buffer 0
    float* wt1 = smem + 8192;   // buffer 1
    const int row0 = blockIdx.x * 8;

    {
        const float4* src = (const float4*)(x + (size_t)row0 * F_IN);
        float4* dst = (float4*)xs;
        #pragma unroll
        for (int i = 0; i < 4; ++i) dst[t + i * 256] = src[t + i * 256];
    }
    const float4* w1v = (const float4*)W1;
    {
        float4* d = (float4*)wt0;
        #pragma unroll
        for (int i = 0; i < 4; ++i) d[t + i * 256] = w1v[t + i * 256];
    }

    const int c = t & 63;
    const int rq = t >> 6;          // 0..3 -> rows rq and rq+4
    float a0 = 0.f, a1 = 0.f;
    float* wcur = wt0;
    float* wnxt = wt1;
    for (int tile = 0; tile < 8; ++tile) {
        __syncthreads();   // buf[cur] (and xs on tile 0) visible to all
        float4 pf0, pf1, pf2, pf3;
        if (tile < 7) {    // issue next tile's loads; latency hides under FMAs
            const float4* s = w1v + (size_t)(tile + 1) * 1024;
            pf0 = s[t]; pf1 = s[t + 256]; pf2 = s[t + 512]; pf3 = s[t + 768];
        }
        const float4* xr0 = (const float4*)&xs[rq * F_IN + tile * 64];
        const float4* xr1 = (const float4*)&xs[(rq + 4) * F_IN + tile * 64];
        #pragma unroll
        for (int kk = 0; kk < 64; kk += 4) {
            float4 x0 = xr0[kk >> 2];
            float4 x1 = xr1[kk >> 2];
            float w0 = wcur[(kk + 0) * 64 + c];
            float w1 = wcur[(kk + 1) * 64 + c];
            float w2 = wcur[(kk + 2) * 64 + c];
            float w3 = wcur[(kk + 3) * 64 + c];
            a0 += x0.x * w0 + x0.y * w1 + x0.z * w2 + x0.w * w3;
            a1 += x1.x * w0 + x1.y * w1 + x1.z * w2 + x1.w * w3;
        }
        if (tile < 7) {    // write into the OTHER buffer; safe w/ 1 barrier
            float4* d = (float4*)wnxt;
            d[t] = pf0; d[t + 256] = pf1; d[t + 512] = pf2; d[t + 768] = pf3;
        }
        float* tmp = wcur; wcur = wnxt; wnxt = tmp;
    }

    // epilogue: h1 + fused es/ed for both rows
    const int n0 = row0 + rq;
    h1[(size_t)n0 * F1 + c] = a0;
    h1[(size_t)(n0 + 4) * F1 + c] = a1;
    float s0 = a0 * asrc[c], d0 = a0 * adst[c];
    float s1 = a1 * asrc[c], d1 = a1 * adst[c];
    s0 += __shfl_xor(s0, 1); s0 += __shfl_xor(s0, 2); s0 += __shfl_xor(s0, 4);
    d0 += __shfl_xor(d0, 1); d0 += __shfl_xor(d0, 2); d0 += __shfl_xor(d0, 4);
    s1 += __shfl_xor(s1, 1); s1 += __shfl_xor(s1, 2); s1 += __shfl_xor(s1, 4);
    d1 += __shfl_xor(d1, 1); d1 += __shfl_xor(d1, 2); d1 += __shfl_xor(d1, 4);
    if ((c & 7) == 0) {
        es[n0 * NH1 + (c >> 3)] = s0;
        ed[n0 * NH1 + (c >> 3)] = d0;
        es[(n0 + 4) * NH1 + (c >> 3)] = s1;
        ed[(n0 + 4) * NH1 + (c >> 3)] = d1;
    }
}

// ---------------------------------------------------------------------------
// Attention layer 1 + ELU + fused gemm2/scores2 (R3-validated, verbatim).
// ---------------------------------------------------------------------------
__global__ __launch_bounds__(256) void attn1_kernel(
        const unsigned short* __restrict__ neigh, const int* __restrict__ deg,
        const float* __restrict__ h1, const float* __restrict__ es,
        const float* __restrict__ ed, const float* __restrict__ W2,
        const float* __restrict__ a2s, const float* __restrict__ a2d,
        float* __restrict__ h2, float* __restrict__ es2, float* __restrict__ ed2) {
    __shared__ float pbufA[4 * 576];
    __shared__ float arowA[4 * 64];
    const int t = threadIdx.x;
    const int wv = t >> 6;
    const int l = t & 63;
    const int i = blockIdx.x * 4 + wv;
    float* pw   = pbufA + wv * 576;
    float* arow = arowA + wv * 64;
    const int hq = l >> 3;

    const int K = deg[i];
    const unsigned short* lst = neigh + (size_t)i * MAXDEG;

    float plsum[NH1];
    #pragma unroll
    for (int h = 0; h < NH1; ++h) plsum[h] = 0.f;
    const float4 e0 = *(const float4*)(es + (size_t)i * NH1);
    const float4 e1 = *(const float4*)(es + (size_t)i * NH1 + 4);
    const float esi[NH1] = {e0.x, e0.y, e0.z, e0.w, e1.x, e1.y, e1.z, e1.w};
    float acc = 0.f;

    for (int t0 = 0; t0 < K; t0 += 64) {
        const int tc = min(64, K - t0);
        const bool valid = l < tc;
        const int j = valid ? (int)lst[t0 + l] : 0;
        const float4 d0v = *(const float4*)(ed + (size_t)j * NH1);
        const float4 d1v = *(const float4*)(ed + (size_t)j * NH1 + 4);
        const float edv[NH1] = {d0v.x, d0v.y, d0v.z, d0v.w,
                                d1v.x, d1v.y, d1v.z, d1v.w};
        #pragma unroll
        for (int h = 0; h < NH1; ++h) {
            float v = esi[h] + edv[h];
            v = (v >= 0.f) ? v : 0.2f * v;      // LeakyReLU(0.2)
            float p = valid ? __expf(v) : 0.f;  // no max-shift: |v|<~4
            plsum[h] += p;
            pw[l * 9 + h] = p;
        }
        __builtin_amdgcn_wave_barrier();
        const int tcPad = (tc + 7) & ~7;
        for (int u = 0; u < tcPad; u += 8) {
            #pragma unroll
            for (int vv = 0; vv < 8; ++vv) {
                const int slot = u + vv;
                const int jn = __shfl(j, slot);     // broadcast neighbor id
                acc += pw[slot * 9 + hq] * h1[(size_t)jn * F1 + l];
            }
        }
        __builtin_amdgcn_wave_barrier();
    }
    float lsum[NH1];
    #pragma unroll
    for (int h = 0; h < NH1; ++h) lsum[h] = wave_sum(plsum[h]);
    float o = acc / lsum[hq];
    float a1v = (o > 0.f) ? o : (__expf(o) - 1.f);  // ELU

    // fused gemm2 + scores2 (row-local, per-wave)
    arow[l] = a1v;
    __builtin_amdgcn_wave_barrier();
    const int cc = l & 15;
    const int kg = l >> 4;
    float hacc = 0.f;
    #pragma unroll
    for (int k = 0; k < 16; ++k)
        hacc += arow[kg * 16 + k] * W2[(kg * 16 + k) * C2 + cc];
    hacc += __shfl_xor(hacc, 16);
    hacc += __shfl_xor(hacc, 32);
    if (l < C2) h2[(size_t)i * C2 + l] = hacc;
    float s2 = hacc * a2s[cc];
    float d2 = hacc * a2d[cc];
    s2 += __shfl_xor(s2, 1); s2 += __shfl_xor(s2, 2);
    s2 += __shfl_xor(s2, 4); s2 += __shfl_xor(s2, 8);
    d2 += __shfl_xor(d2, 1); d2 += __shfl_xor(d2, 2);
    d2 += __shfl_xor(d2, 4); d2 += __shfl_xor(d2, 8);
    if (l == 0) { es2[i] = s2; ed2[i] = d2; }
}

// ---------------------------------------------------------------------------
// Attention layer 2 — LDS-free (R3-validated, verbatim).
// ---------------------------------------------------------------------------
__global__ __launch_bounds__(256) void attn2_kernel(
        const unsigned short* __restrict__ neigh, const int* __restrict__ deg,
        const float* __restrict__ h2, const float* __restrict__ es2,
        const float* __restrict__ ed2, float* __restrict__ out) {
    const int t = threadIdx.x;
    const int wv = t >> 6;
    const int l = t & 63;
    const int i = blockIdx.x * 4 + wv;
    const int c = l & 15;
    const int g = l >> 4;

    const int K = deg[i];
    const unsigned short* lst = neigh + (size_t)i * MAXDEG;

    float plsum = 0.f, acc = 0.f;
    const float esi = es2[i];
    for (int t0 = 0; t0 < K; t0 += 64) {
        const int tc = min(64, K - t0);
        const bool valid = l < tc;
        const int j = valid ? (int)lst[t0 + l] : 0;
        float v = esi + ed2[j];
        v = (v >= 0.f) ? v : 0.2f * v;
        float p = valid ? __expf(v) : 0.f;   // no max-shift
        plsum += p;
        const int tcPad = (tc + 3) & ~3;
        for (int u = g; u < tcPad; u += 4) {
            const int jn = __shfl(j, u);     // per-group broadcast
            const float pv = __shfl(p, u);
            acc += pv * h2[(size_t)jn * C2 + c];
        }
    }
    float lsum = wave_sum(plsum);    // wave-uniform
    acc += __shfl_xor(acc, 16);
    acc += __shfl_xor(acc, 32);
    if (l < C2) out[(size_t)i * C2 + l] = acc / lsum;
}

extern "C" void kernel_launch(void* const* d_in, const int* in_sizes, int n_in,
                              void* d_out, int out_size, void* d_ws, size_t ws_size,
                              hipStream_t stream) {
    const float* x           = (const float*)d_in[0];
    const unsigned char* adj = (const unsigned char*)d_in[1];
    const float* W1          = (const float*)d_in[2];
    const float* a1src       = (const float*)d_in[3];
    const float* a1dst       = (const float*)d_in[4];
    const float* W2          = (const float*)d_in[5];
    const float* a2src       = (const float*)d_in[6];
    const float* a2dst       = (const float*)d_in[7];
    float* out = (float*)d_out;

    // workspace layout (~2.6 MB), all offsets 256B-aligned
    char* ws = (char*)d_ws;
    size_t off = 0;
    off += 256;                                       // (reserved)
    unsigned short* neigh = (unsigned short*)(ws + off);
    off += (size_t)N_NODES * MAXDEG * 2;              // 1 MB
    int* deg = (int*)(ws + off);                      off += (size_t)N_NODES * 4;
    float* h1 = (float*)(ws + off);                   off += (size_t)N_NODES * F1 * 4;
    float* es1 = (float*)(ws + off);                  off += (size_t)N_NODES * NH1 * 4;
    float* ed1 = (float*)(ws + off);                  off += (size_t)N_NODES * NH1 * 4;
    float* h2 = (float*)(ws + off);                   off += (size_t)N_NODES * C2 * 4;
    float* es2 = (float*)(ws + off);                  off += (size_t)N_NODES * 4;
    float* ed2 = (float*)(ws + off);                  off += (size_t)N_NODES * 4;

    hipLaunchKernelGGL(scan_kernel, dim3(SCAN_BLKS), dim3(256), 0, stream,
                       adj, neigh, deg);
    hipLaunchKernelGGL(gemm_kernel, dim3(GEMM_BLKS), dim3(256), 0, stream,
                       x, W1, a1src, a1dst, h1, es1, ed1);
    hipLaunchKernelGGL(attn1_kernel, dim3(N_NODES / 4), dim3(256), 0, stream,
                       neigh, deg, h1, es1, ed1, W2, a2src, a2dst, h2, es2, ed2);
    hipLaunchKernelGGL(attn2_kernel, dim3(N_NODES / 4), dim3(256), 0, stream,
                       neigh, deg, h2, es2, ed2, out);
}

// Round 6
// 127.673 us; speedup vs baseline: 1.3284x; 1.0810x over previous
//
#include <hip/hip_runtime.h>

#define N_NODES 4096
#define F_IN    512
#define NH1     8
#define F1      64   // NH1*ND1
#define C2      16
#define MAXDEG  128  // Binomial(4095,0.005): mean 20.5, max ~50; 128 unreachable

#define GEMM_BLKS 512    // 8 rows each -> 4096 rows
#define SCAN_BLKS 512    // 8 rows each (2 rows/wave)

__device__ __forceinline__ float wave_sum(float v) {
    for (int o = 32; o >= 1; o >>= 1) v += __shfl_xor(v, o, 64);
    return v;
}

// ---------------------------------------------------------------------------
// Per-wave adjacency element-width detection from the first 4 KB of adj.
// Validated classification rules; wave-ballot reduction; wave-uniform result.
// ---------------------------------------------------------------------------
__device__ __forceinline__ int detect_width_wave(const unsigned char* __restrict__ adj,
                                                 int l) {
    bool nz0 = false, nz1 = false, nz2 = false, nz3 = false;
    unsigned int mx = 0u;
    const uint4* p = (const uint4*)adj;
    #pragma unroll
    for (int i = 0; i < 4; ++i) {          // 64 lanes * 4 * 16B = 4 KB
        uint4 q = p[l + 64 * i];
        unsigned int wd[4] = {q.x, q.y, q.z, q.w};
        #pragma unroll
        for (int k = 0; k < 4; ++k) {
            unsigned int v = wd[k];
            unsigned int b0 = v & 0xffu, b1 = (v >> 8) & 0xffu;
            unsigned int b2 = (v >> 16) & 0xffu, b3 = (v >> 24) & 0xffu;
            if (b0) { nz0 = true; mx = mx > b0 ? mx : b0; }
            if (b1) { nz1 = true; mx = mx > b1 ? mx : b1; }
            if (b2) { nz2 = true; mx = mx > b2 ? mx : b2; }
            if (b3) { nz3 = true; mx = mx > b3 ? mx : b3; }
        }
    }
    const bool a0 = __any(nz0), a1 = __any(nz1), a2 = __any(nz2), a3 = __any(nz3);
    const bool big = __any(mx > 1u);
    if (!a1 && !a2 && !a3) return 4;   // int32 {0,1}: only byte 0 of each dword
    if (!a0 && !a1)        return 4;   // fp32 1.0f: bytes 2,3
    if (!a0 && !a2)        return 2;   // f16 1.0: odd bytes only
    if (!big)              return 1;   // bool/uint8 {0,1}
    return 2;                          // bf16 1.0
}

// ---------------------------------------------------------------------------
// Ballot-compaction row scan (R5-validated body): one wave scans one row with
// ZERO atomics; 64-bit nonzero mask + shfl_up exclusive prefix.
// ---------------------------------------------------------------------------
__device__ __forceinline__ void scan_row(const unsigned char* __restrict__ adj,
                                         int w, int row, int l,
                                         unsigned short* __restrict__ neigh,
                                         int* __restrict__ deg) {
    unsigned short* outp = neigh + (size_t)row * MAXDEG;
    unsigned long long mask = 0ull;
    int eshift;
    if (w == 1) {
        eshift = 4;                                  // 16 elements / 16B chunk
        const uint4* p = (const uint4*)(adj + (size_t)row * N_NODES);
        uint4 v[4];
        #pragma unroll
        for (int i = 0; i < 4; ++i) v[i] = p[l + 64 * i];   // 4 loads in flight
        #pragma unroll
        for (int i = 0; i < 4; ++i) {
            unsigned int wd[4] = {v[i].x, v[i].y, v[i].z, v[i].w};
            #pragma unroll
            for (int q = 0; q < 4; ++q) {
                unsigned int x = wd[q];
                // 0x80 in each nonzero byte
                unsigned int tt = (x | ((x & 0x7f7f7f7fu) + 0x7f7f7f7fu)) & 0x80808080u;
                // gather the 4 flag bits into a nibble
                unsigned int nib = ((tt >> 7) * 0x01020408u) >> 24;
                mask |= (unsigned long long)nib << (16 * i + 4 * q);
            }
        }
    } else if (w == 2) {
        eshift = 3;                                  // 8 elements / 16B chunk
        const uint4* p = (const uint4*)(adj + (size_t)row * N_NODES * 2);
        uint4 v[8];
        #pragma unroll
        for (int i = 0; i < 8; ++i) v[i] = p[l + 64 * i];
        #pragma unroll
        for (int i = 0; i < 8; ++i) {
            unsigned int wd[4] = {v[i].x, v[i].y, v[i].z, v[i].w};
            #pragma unroll
            for (int q = 0; q < 4; ++q) {
                unsigned int x = wd[q];
                unsigned int b = ((x & 0xffffu) ? 1u : 0u) | ((x >> 16) ? 2u : 0u);
                mask |= (unsigned long long)b << (8 * i + 2 * q);
            }
        }
    } else {
        eshift = 2;                                  // 4 elements / 16B chunk
        const uint4* p = (const uint4*)(adj + (size_t)row * N_NODES * 4);
        #pragma unroll
        for (int b2 = 0; b2 < 2; ++b2) {
            uint4 v[8];
            #pragma unroll
            for (int i = 0; i < 8; ++i) v[i] = p[l + 64 * (b2 * 8 + i)];
            #pragma unroll
            for (int i = 0; i < 8; ++i) {
                unsigned int wd[4] = {v[i].x, v[i].y, v[i].z, v[i].w};
                #pragma unroll
                for (int q = 0; q < 4; ++q)
                    if (wd[q]) mask |= 1ull << (4 * (b2 * 8 + i) + q);
            }
        }
    }

    // wave-wide compaction
    const int cnt = __popcll(mask);
    int pfx = cnt;
    #pragma unroll
    for (int o = 1; o < 64; o <<= 1) {
        int up = __shfl_up(pfx, o, 64);
        if (l >= o) pfx += up;
    }
    int base = pfx - cnt;                 // exclusive prefix
    unsigned long long m = mask;
    while (m) {
        const int b = __builtin_ctzll(m);
        m &= m - 1;
        const int e = ((b >> eshift) << (eshift + 6)) + (l << eshift)
                    + (b & ((1 << eshift) - 1));
        if (base < MAXDEG) outp[base] = (unsigned short)e;
        ++base;
    }
    if (l == 63) deg[row] = min(pfx, MAXDEG);
}

// ---------------------------------------------------------------------------
// Merged front-end: scan and GEMM are INDEPENDENT, so they share one dispatch
// and overlap on the CUs (scan = HBM-latency-bound, GEMM = LDS/VALU-bound —
// complementary pipes). 32 KB LDS / ~64 VGPR => 4 blocks/CU: the full
// 1024-block grid is co-resident.
//   blocks [0, GEMM_BLKS):   GEMM1 + fused es/ed (R2-validated body: 8 rows,
//                            2 out/lane, xs + single wt + register prefetch).
//   blocks [GEMM_BLKS, ...): ballot scan, 2 rows/wave (R5-validated body).
// ---------------------------------------------------------------------------
__global__ __launch_bounds__(256) void frontend_kernel(
        const unsigned char* __restrict__ adj,
        unsigned short* __restrict__ neigh, int* __restrict__ deg,
        const float* __restrict__ x, const float* __restrict__ W1,
        const float* __restrict__ asrc, const float* __restrict__ adst,
        float* __restrict__ h1, float* __restrict__ es, float* __restrict__ ed) {
    __shared__ __align__(16) float smem[8192];   // 32 KB: xs 16 KB + wt 16 KB
    const int t = threadIdx.x;
    const int wv = t >> 6;
    const int l = t & 63;

    if (blockIdx.x < GEMM_BLKS) {
        // ---- GEMM1: rows row0..row0+7, cols 0..63 (R2-validated) ----
        float* xs = smem;            // 8*512 floats = 16 KB
        float* wt = smem + 4096;     // 64*64 floats = 16 KB
        const int row0 = blockIdx.x * 8;
        {
            const float4* src = (const float4*)(x + (size_t)row0 * F_IN);
            float4* dst = (float4*)xs;
            #pragma unroll
            for (int i = 0; i < 4; ++i) dst[t + i * 256] = src[t + i * 256];
        }
        const float4* w1v = (const float4*)W1;
        float4* wtv = (float4*)wt;
        #pragma unroll
        for (int i = 0; i < 4; ++i) wtv[t + i * 256] = w1v[t + i * 256];

        const int c = l;
        float a0 = 0.f, a1 = 0.f;
        for (int tile = 0; tile < 8; ++tile) {
            __syncthreads();                 // wt[tile] (+xs on tile 0) ready
            float4 pf0, pf1, pf2, pf3;
            if (tile < 7) {                  // prefetch next tile into regs
                const float4* s = w1v + (size_t)(tile + 1) * 1024;
                pf0 = s[t]; pf1 = s[t + 256]; pf2 = s[t + 512]; pf3 = s[t + 768];
            }
            const float4* xr0 = (const float4*)&xs[wv * F_IN + tile * 64];
            const float4* xr1 = (const float4*)&xs[(wv + 4) * F_IN + tile * 64];
            #pragma unroll
            for (int kk = 0; kk < 64; kk += 4) {
                float4 x0 = xr0[kk >> 2];
                float4 x1 = xr1[kk >> 2];
                float w0 = wt[(kk + 0) * 64 + c];
                float w1 = wt[(kk + 1) * 64 + c];
                float w2 = wt[(kk + 2) * 64 + c];
                float w3 = wt[(kk + 3) * 64 + c];
                a0 += x0.x * w0 + x0.y * w1 + x0.z * w2 + x0.w * w3;
                a1 += x1.x * w0 + x1.y * w1 + x1.z * w2 + x1.w * w3;
            }
            __syncthreads();                 // all reads of wt done
            if (tile < 7) {
                wtv[t] = pf0; wtv[t + 256] = pf1;
                wtv[t + 512] = pf2; wtv[t + 768] = pf3;
            }
        }
        const int n0 = row0 + wv;
        h1[(size_t)n0 * F1 + c] = a0;
        h1[(size_t)(n0 + 4) * F1 + c] = a1;
        float s0 = a0 * asrc[c], d0 = a0 * adst[c];
        float s1 = a1 * asrc[c], d1 = a1 * adst[c];
        s0 += __shfl_xor(s0, 1); s0 += __shfl_xor(s0, 2); s0 += __shfl_xor(s0, 4);
        d0 += __shfl_xor(d0, 1); d0 += __shfl_xor(d0, 2); d0 += __shfl_xor(d0, 4);
        s1 += __shfl_xor(s1, 1); s1 += __shfl_xor(s1, 2); s1 += __shfl_xor(s1, 4);
        d1 += __shfl_xor(d1, 1); d1 += __shfl_xor(d1, 2); d1 += __shfl_xor(d1, 4);
        if ((c & 7) == 0) {
            es[n0 * NH1 + (c >> 3)] = s0;
            ed[n0 * NH1 + (c >> 3)] = d0;
            es[(n0 + 4) * NH1 + (c >> 3)] = s1;
            ed[(n0 + 4) * NH1 + (c >> 3)] = d1;
        }
    } else {
        // ---- ballot scan: 8 rows/block, 2 rows/wave ----
        const int w = detect_width_wave(adj, l);
        const int rbase = (blockIdx.x - GEMM_BLKS) * 8 + wv * 2;
        scan_row(adj, w, rbase + 0, l, neigh, deg);
        scan_row(adj, w, rbase + 1, l, neigh, deg);
    }
}

// ---------------------------------------------------------------------------
// Attention layer 1 + ELU + fused gemm2/scores2 (R3-validated, verbatim).
// ---------------------------------------------------------------------------
__global__ __launch_bounds__(256) void attn1_kernel(
        const unsigned short* __restrict__ neigh, const int* __restrict__ deg,
        const float* __restrict__ h1, const float* __restrict__ es,
        const float* __restrict__ ed, const float* __restrict__ W2,
        const float* __restrict__ a2s, const float* __restrict__ a2d,
        float* __restrict__ h2, float* __restrict__ es2, float* __restrict__ ed2) {
    __shared__ float pbufA[4 * 576];
    __shared__ float arowA[4 * 64];
    const int t = threadIdx.x;
    const int wv = t >> 6;
    const int l = t & 63;
    const int i = blockIdx.x * 4 + wv;
    float* pw   = pbufA + wv * 576;
    float* arow = arowA + wv * 64;
    const int hq = l >> 3;

    const int K = deg[i];
    const unsigned short* lst = neigh + (size_t)i * MAXDEG;

    float plsum[NH1];
    #pragma unroll
    for (int h = 0; h < NH1; ++h) plsum[h] = 0.f;
    const float4 e0 = *(const float4*)(es + (size_t)i * NH1);
    const float4 e1 = *(const float4*)(es + (size_t)i * NH1 + 4);
    const float esi[NH1] = {e0.x, e0.y, e0.z, e0.w, e1.x, e1.y, e1.z, e1.w};
    float acc = 0.f;

    for (int t0 = 0; t0 < K; t0 += 64) {
        const int tc = min(64, K - t0);
        const bool valid = l < tc;
        const int j = valid ? (int)lst[t0 + l] : 0;
        const float4 d0v = *(const float4*)(ed + (size_t)j * NH1);
        const float4 d1v = *(const float4*)(ed + (size_t)j * NH1 + 4);
        const float edv[NH1] = {d0v.x, d0v.y, d0v.z, d0v.w,
                                d1v.x, d1v.y, d1v.z, d1v.w};
        #pragma unroll
        for (int h = 0; h < NH1; ++h) {
            float v = esi[h] + edv[h];
            v = (v >= 0.f) ? v : 0.2f * v;      // LeakyReLU(0.2)
            float p = valid ? __expf(v) : 0.f;  // no max-shift: |v|<~4
            plsum[h] += p;
            pw[l * 9 + h] = p;
        }
        __builtin_amdgcn_wave_barrier();
        const int tcPad = (tc + 7) & ~7;
        for (int u = 0; u < tcPad; u += 8) {
            #pragma unroll
            for (int vv = 0; vv < 8; ++vv) {
                const int slot = u + vv;
                const int jn = __shfl(j, slot);     // broadcast neighbor id
                acc += pw[slot * 9 + hq] * h1[(size_t)jn * F1 + l];
            }
        }
        __builtin_amdgcn_wave_barrier();
    }
    float lsum[NH1];
    #pragma unroll
    for (int h = 0; h < NH1; ++h) lsum[h] = wave_sum(plsum[h]);
    float o = acc / lsum[hq];
    float a1v = (o > 0.f) ? o : (__expf(o) - 1.f);  // ELU

    // fused gemm2 + scores2 (row-local, per-wave)
    arow[l] = a1v;
    __builtin_amdgcn_wave_barrier();
    const int cc = l & 15;
    const int kg = l >> 4;
    float hacc = 0.f;
    #pragma unroll
    for (int k = 0; k < 16; ++k)
        hacc += arow[kg * 16 + k] * W2[(kg * 16 + k) * C2 + cc];
    hacc += __shfl_xor(hacc, 16);
    hacc += __shfl_xor(hacc, 32);
    if (l < C2) h2[(size_t)i * C2 + l] = hacc;
    float s2 = hacc * a2s[cc];
    float d2 = hacc * a2d[cc];
    s2 += __shfl_xor(s2, 1); s2 += __shfl_xor(s2, 2);
    s2 += __shfl_xor(s2, 4); s2 += __shfl_xor(s2, 8);
    d2 += __shfl_xor(d2, 1); d2 += __shfl_xor(d2, 2);
    d2 += __shfl_xor(d2, 4); d2 += __shfl_xor(d2, 8);
    if (l == 0) { es2[i] = s2; ed2[i] = d2; }
}

// ---------------------------------------------------------------------------
// Attention layer 2 — LDS-free (R3-validated, verbatim).
// ---------------------------------------------------------------------------
__global__ __launch_bounds__(256) void attn2_kernel(
        const unsigned short* __restrict__ neigh, const int* __restrict__ deg,
        const float* __restrict__ h2, const float* __restrict__ es2,
        const float* __restrict__ ed2, float* __restrict__ out) {
    const int t = threadIdx.x;
    const int wv = t >> 6;
    const int l = t & 63;
    const int i = blockIdx.x * 4 + wv;
    const int c = l & 15;
    const int g = l >> 4;

    const int K = deg[i];
    const unsigned short* lst = neigh + (size_t)i * MAXDEG;

    float plsum = 0.f, acc = 0.f;
    const float esi = es2[i];
    for (int t0 = 0; t0 < K; t0 += 64) {
        const int tc = min(64, K - t0);
        const bool valid = l < tc;
        const int j = valid ? (int)lst[t0 + l] : 0;
        float v = esi + ed2[j];
        v = (v >= 0.f) ? v : 0.2f * v;
        float p = valid ? __expf(v) : 0.f;   // no max-shift
        plsum += p;
        const int tcPad = (tc + 3) & ~3;
        for (int u = g; u < tcPad; u += 4) {
            const int jn = __shfl(j, u);     // per-group broadcast
            const float pv = __shfl(p, u);
            acc += pv * h2[(size_t)jn * C2 + c];
        }
    }
    float lsum = wave_sum(plsum);    // wave-uniform
    acc += __shfl_xor(acc, 16);
    acc += __shfl_xor(acc, 32);
    if (l < C2) out[(size_t)i * C2 + l] = acc / lsum;
}

extern "C" void kernel_launch(void* const* d_in, const int* in_sizes, int n_in,
                              void* d_out, int out_size, void* d_ws, size_t ws_size,
                              hipStream_t stream) {
    const float* x           = (const float*)d_in[0];
    const unsigned char* adj = (const unsigned char*)d_in[1];
    const float* W1          = (const float*)d_in[2];
    const float* a1src       = (const float*)d_in[3];
    const float* a1dst       = (const float*)d_in[4];
    const float* W2          = (const float*)d_in[5];
    const float* a2src       = (const float*)d_in[6];
    const float* a2dst       = (const float*)d_in[7];
    float* out = (float*)d_out;

    // workspace layout (~2.6 MB), all offsets 256B-aligned
    char* ws = (char*)d_ws;
    size_t off = 0;
    off += 256;                                       // (reserved)
    unsigned short* neigh = (unsigned short*)(ws + off);
    off += (size_t)N_NODES * MAXDEG * 2;              // 1 MB
    int* deg = (int*)(ws + off);                      off += (size_t)N_NODES * 4;
    float* h1 = (float*)(ws + off);                   off += (size_t)N_NODES * F1 * 4;
    float* es1 = (float*)(ws + off);                  off += (size_t)N_NODES * NH1 * 4;
    float* ed1 = (float*)(ws + off);                  off += (size_t)N_NODES * NH1 * 4;
    float* h2 = (float*)(ws + off);                   off += (size_t)N_NODES * C2 * 4;
    float* es2 = (float*)(ws + off);                  off += (size_t)N_NODES * 4;
    float* ed2 = (float*)(ws + off);                  off += (size_t)N_NODES * 4;

    hipLaunchKernelGGL(frontend_kernel, dim3(GEMM_BLKS + SCAN_BLKS), dim3(256), 0, stream,
                       adj, neigh, deg, x, W1, a1src, a1dst, h1, es1, ed1);
    hipLaunchKernelGGL(attn1_kernel, dim3(N_NODES / 4), dim3(256), 0, stream,
                       neigh, deg, h1, es1, ed1, W2, a2src, a2dst, h2, es2, ed2);
    hipLaunchKernelGGL(attn2_kernel, dim3(N_NODES / 4), dim3(256), 0, stream,
                       neigh, deg, h2, es2, ed2, out);
}